// Round 1
// baseline (1484.149 us; speedup 1.0000x reference)
//
#include <hip/hip_runtime.h>
#include <hip/hip_fp16.h>
#include <math.h>

#define B_ 256
#define C_ 3
#define IMG_ 32
#define D_ 256
#define H_ 8
#define HD_ 32
#define T1_ 65
#define MLP_H_ 2048
#define HEAD_H_ 8192
#define NCLS 10
#define PDIM 48
#define M_ROWS (B_*T1_)   // 16640

typedef _Float16 f16;
typedef _Float16 f16x8 __attribute__((ext_vector_type(8)));
typedef _Float16 f16x4 __attribute__((ext_vector_type(4)));
typedef float f32x4 __attribute__((ext_vector_type(4)));

// ---------------- patch embed + cls + positional encoding ----------------
__global__ __launch_bounds__(256) void patch_embed_kernel(
        const float* __restrict__ x, const float* __restrict__ cls,
        const float* __restrict__ Wp, const float* __restrict__ bp,
        float* __restrict__ out) {
    int bt = blockIdx.x;           // b*T1 + t
    int b = bt / T1_;
    int t = bt % T1_;
    int d = threadIdx.x;           // 0..255
    // positional encoding: pe[t, 2i]=sin(t*div_i), pe[t,2i+1]=cos(t*div_i)
    int i2 = d & ~1;
    float div = expf((float)i2 * (-9.210340371976184f / 256.0f));
    float ang = (float)t * div;
    float pe = (d & 1) ? cosf(ang) : sinf(ang);

    __shared__ float patch[PDIM];
    if (t > 0) {
        int p = t - 1;
        int py = p >> 3, px = p & 7;
        if (threadIdx.x < PDIM) {
            int j = threadIdx.x;
            int c = j >> 4, r = j & 15;
            int iy = r >> 2, ix = r & 3;
            patch[j] = x[((b * C_ + c) * IMG_ + py * 4 + iy) * IMG_ + px * 4 + ix];
        }
    }
    __syncthreads();
    float acc;
    if (t == 0) {
        acc = cls[d];
    } else {
        acc = bp[d];
        #pragma unroll
        for (int j = 0; j < PDIM; ++j) acc += patch[j] * Wp[j * D_ + d];
    }
    out[(size_t)bt * D_ + d] = acc + pe;
}

// ---------------- LayerNorm over (T1,D) per batch, write fp16 ----------------
__global__ __launch_bounds__(256) void ln_kernel(
        const float* __restrict__ xin, const float* __restrict__ w,
        const float* __restrict__ bb, f16* __restrict__ hout) {
    int b = blockIdx.x;
    const float* xb = xin + (size_t)b * (T1_ * D_);
    float s = 0.f, s2 = 0.f;
    for (int i = threadIdx.x; i < T1_ * D_; i += 256) {
        float v = xb[i]; s += v; s2 += v * v;
    }
    #pragma unroll
    for (int o = 32; o > 0; o >>= 1) { s += __shfl_down(s, o); s2 += __shfl_down(s2, o); }
    __shared__ float rs[4], rs2[4];
    __shared__ float mu_s, rstd_s;
    int wid = threadIdx.x >> 6;
    if ((threadIdx.x & 63) == 0) { rs[wid] = s; rs2[wid] = s2; }
    __syncthreads();
    if (threadIdx.x == 0) {
        float S = rs[0] + rs[1] + rs[2] + rs[3];
        float S2 = rs2[0] + rs2[1] + rs2[2] + rs2[3];
        const float inv_n = 1.0f / (float)(T1_ * D_);
        float mu = S * inv_n;
        float var = S2 * inv_n - mu * mu;
        mu_s = mu; rstd_s = rsqrtf(var + 1e-5f);
    }
    __syncthreads();
    float mu = mu_s, rstd = rstd_s;
    f16* hb = hout + (size_t)b * (T1_ * D_);
    for (int i = threadIdx.x; i < T1_ * D_; i += 256) {
        float v = (xb[i] - mu) * rstd * w[i] + bb[i];
        hb[i] = (f16)v;
    }
}

// ---------------- fp16 MFMA GEMM: C = A(f16, MxK) * B(f32->f16, KxN) ----------
// EPI: 0 = +bias (float out), 1 = +bias,relu (f16 out), 2 = +bias+residual (float out),
//      4 = raw partial (float out, split-K via blockIdx.z)
template<int EPI, typename OutT>
__global__ __launch_bounds__(256) void gemm_kernel(
        const f16* __restrict__ A, const float* __restrict__ Bw,
        const float* __restrict__ bias, const float* __restrict__ Res,
        OutT* __restrict__ Cc, int M, int N, int K) {
    const int BM = 128, BN = 128, BK = 32;
    __shared__ f16 As[128][40];   // [m][k], pad to 40 halves
    __shared__ f16 Bs[128][40];   // [n][k] (transposed), pad to 40 halves
    int nb = blockIdx.x, mb = blockIdx.y;
    int tid = threadIdx.x;
    int lane = tid & 63, wid = tid >> 6;
    int wr = wid >> 1, wc = wid & 1;
    int lr = lane & 15, kq = lane >> 4;
    int row0 = mb * BM, col0 = nb * BN;

    f32x4 acc[4][4];
    #pragma unroll
    for (int mi = 0; mi < 4; ++mi)
        #pragma unroll
        for (int ni = 0; ni < 4; ++ni)
            #pragma unroll
            for (int r = 0; r < 4; ++r) acc[mi][ni][r] = 0.f;

    int a_row = tid >> 1, a_kk = (tid & 1) * 16;
    int b_kr = (tid >> 5) * 4;      // 8 groups * 4 k-rows = 32
    int b_nc = (tid & 31) * 4;      // 32 groups * 4 cols  = 128

    int kpb = K / gridDim.z;
    int kstart = blockIdx.z * kpb;

    for (int k0 = kstart; k0 < kstart + kpb; k0 += BK) {
        __syncthreads();
        // A tile: 128x32 f16, 16 halves per thread
        {
            const f16* ag = A + (size_t)(row0 + a_row) * K + k0 + a_kk;
            *(f16x8*)&As[a_row][a_kk]     = *(const f16x8*)(ag);
            *(f16x8*)&As[a_row][a_kk + 8] = *(const f16x8*)(ag + 8);
        }
        // B tile: 32x128 f32 -> transposed f16 [n][k]
        {
            float tmp[4][4];
            #pragma unroll
            for (int i = 0; i < 4; ++i) {
                const float4 v = *(const float4*)(Bw + (size_t)(k0 + b_kr + i) * N + col0 + b_nc);
                tmp[0][i] = v.x; tmp[1][i] = v.y; tmp[2][i] = v.z; tmp[3][i] = v.w;
            }
            #pragma unroll
            for (int j = 0; j < 4; ++j) {
                f16x4 hv;
                hv[0] = (f16)tmp[j][0]; hv[1] = (f16)tmp[j][1];
                hv[2] = (f16)tmp[j][2]; hv[3] = (f16)tmp[j][3];
                *(f16x4*)&Bs[b_nc + j][b_kr] = hv;
            }
        }
        __syncthreads();
        f16x8 af[4], bf[4];
        #pragma unroll
        for (int mi = 0; mi < 4; ++mi) af[mi] = *(f16x8*)&As[wr * 64 + mi * 16 + lr][kq * 8];
        #pragma unroll
        for (int ni = 0; ni < 4; ++ni) bf[ni] = *(f16x8*)&Bs[wc * 64 + ni * 16 + lr][kq * 8];
        #pragma unroll
        for (int mi = 0; mi < 4; ++mi)
            #pragma unroll
            for (int ni = 0; ni < 4; ++ni)
                acc[mi][ni] = __builtin_amdgcn_mfma_f32_16x16x32_f16(af[mi], bf[ni], acc[mi][ni], 0, 0, 0);
    }

    OutT* Cout = Cc;
    if (EPI == 4) Cout = Cc + (size_t)blockIdx.z * M * N;
    #pragma unroll
    for (int mi = 0; mi < 4; ++mi) {
        #pragma unroll
        for (int ni = 0; ni < 4; ++ni) {
            int col = col0 + wc * 64 + ni * 16 + lr;
            #pragma unroll
            for (int r = 0; r < 4; ++r) {
                int row = row0 + wr * 64 + mi * 16 + kq * 4 + r;
                float v = acc[mi][ni][r];
                if (EPI != 4) v += bias[col];
                if (EPI == 1) v = fmaxf(v, 0.f);
                if (EPI == 2) v += Res[(size_t)row * N + col];
                Cout[(size_t)row * N + col] = (OutT)v;
            }
        }
    }
}

// ---------------- attention (fp32), one block per (b,h); writes r = attn+out ---
__global__ __launch_bounds__(256) void attn_kernel(
        const float* __restrict__ qkv, const float* __restrict__ outres,
        float* __restrict__ r) {
    int bh = blockIdx.x;
    int b = bh >> 3, h = bh & 7;
    __shared__ float q[T1_][HD_], k[T1_][HD_], v[T1_][HD_];
    __shared__ float s[T1_][T1_ + 1];
    const float* base = qkv + (size_t)b * T1_ * 768 + h * 96;
    for (int idx = threadIdx.x; idx < T1_ * 96; idx += 256) {
        int t = idx / 96, rem = idx % 96;
        int j = rem >> 5, d = rem & 31;
        float val = base[(size_t)t * 768 + rem];
        if (j == 0) q[t][d] = val; else if (j == 1) k[t][d] = val; else v[t][d] = val;
    }
    __syncthreads();
    const float scale = 0.17677669529663687f;  // 1/sqrt(32)
    for (int idx = threadIdx.x; idx < T1_ * T1_; idx += 256) {
        int qt = idx / T1_, kt = idx % T1_;
        float acc = 0.f;
        #pragma unroll
        for (int d = 0; d < HD_; ++d) acc += q[qt][d] * k[kt][d];
        s[qt][kt] = acc * scale;
    }
    __syncthreads();
    if (threadIdx.x < T1_) {
        int qt = threadIdx.x;
        float m = -1e30f;
        for (int kt = 0; kt < T1_; ++kt) m = fmaxf(m, s[qt][kt]);
        float sum = 0.f;
        for (int kt = 0; kt < T1_; ++kt) { float e = __expf(s[qt][kt] - m); s[qt][kt] = e; sum += e; }
        float inv = 1.f / sum;
        for (int kt = 0; kt < T1_; ++kt) s[qt][kt] *= inv;
    }
    __syncthreads();
    for (int idx = threadIdx.x; idx < T1_ * HD_; idx += 256) {
        int t = idx >> 5, d = idx & 31;
        float acc = 0.f;
        for (int kt = 0; kt < T1_; ++kt) acc += s[t][kt] * v[kt][d];
        size_t o = (size_t)(b * T1_ + t) * D_ + h * HD_ + d;
        r[o] = acc + outres[o];
    }
}

// ---------------- fp32 -> fp16 convert ----------------
__global__ __launch_bounds__(256) void cvt_kernel(const float* __restrict__ in,
                                                  f16* __restrict__ o, int n) {
    int i = blockIdx.x * 256 + threadIdx.x;
    int stride = gridDim.x * 256;
    for (; i < n; i += stride) o[i] = (f16)in[i];
}

// ---------------- split-K combine + bias + silu ----------------
__global__ __launch_bounds__(256) void combine_silu(const float* __restrict__ part,
                                                    const float* __restrict__ bias,
                                                    float* __restrict__ o) {
    int idx = blockIdx.x * 256 + threadIdx.x;  // 256*8192 total
    const int NP = 256 * HEAD_H_;
    float v = part[idx] + part[idx + NP] + part[idx + 2 * NP] + part[idx + 3 * NP]
            + bias[idx & (HEAD_H_ - 1)];
    o[idx] = v / (1.f + expf(-v));
}

// ---------------- head2: (256,8192) @ (8192,10) + b ----------------
__global__ __launch_bounds__(256) void head2_kernel(
        const float* __restrict__ hidden, const float* __restrict__ w,
        const float* __restrict__ bias, float* __restrict__ out) {
    int b = blockIdx.x;
    const float* hb = hidden + (size_t)b * HEAD_H_;
    float acc[NCLS];
    #pragma unroll
    for (int n = 0; n < NCLS; ++n) acc[n] = 0.f;
    for (int kk = threadIdx.x; kk < HEAD_H_; kk += 256) {
        float hv = hb[kk];
        const float* wr = w + (size_t)kk * NCLS;
        #pragma unroll
        for (int n = 0; n < NCLS; ++n) acc[n] += hv * wr[n];
    }
    #pragma unroll
    for (int n = 0; n < NCLS; ++n)
        #pragma unroll
        for (int o = 32; o > 0; o >>= 1) acc[n] += __shfl_down(acc[n], o);
    __shared__ float red[4][NCLS];
    int wid = threadIdx.x >> 6;
    if ((threadIdx.x & 63) == 0)
        for (int n = 0; n < NCLS; ++n) red[wid][n] = acc[n];
    __syncthreads();
    if (threadIdx.x < NCLS) {
        int n = threadIdx.x;
        out[(size_t)b * NCLS + n] = red[0][n] + red[1][n] + red[2][n] + red[3][n] + bias[n];
    }
}

extern "C" void kernel_launch(void* const* d_in, const int* in_sizes, int n_in,
                              void* d_out, int out_size, void* d_ws, size_t ws_size,
                              hipStream_t stream) {
    (void)in_sizes; (void)n_in; (void)out_size; (void)ws_size;
    const float* x       = (const float*)d_in[0];
    const float* cls     = (const float*)d_in[1];
    const float* Wp      = (const float*)d_in[2];
    const float* bp      = (const float*)d_in[3];
    const float* qkv_w   = (const float*)d_in[4];
    const float* qkv_b   = (const float*)d_in[5];
    const float* ln_w    = (const float*)d_in[6];
    const float* ln_b    = (const float*)d_in[7];
    const float* mlp1_w  = (const float*)d_in[8];
    const float* mlp1_b  = (const float*)d_in[9];
    const float* mlp2_w  = (const float*)d_in[10];
    const float* mlp2_b  = (const float*)d_in[11];
    const float* head1_w = (const float*)d_in[12];
    const float* head1_b = (const float*)d_in[13];
    const float* head2_w = (const float*)d_in[14];
    const float* head2_b = (const float*)d_in[15];
    float* outp = (float*)d_out;

    char* ws = (char*)d_ws;
    size_t off = 0;
    auto alloc = [&](size_t bytes) -> void* {
        void* p = ws + off; off += (bytes + 255) & ~(size_t)255; return p;
    };
    float* s_out = (float*)alloc((size_t)M_ROWS * D_ * 4);        // residual stream
    float* s_r   = (float*)alloc((size_t)M_ROWS * D_ * 4);        // post-attn residual
    f16*   s_h   = (f16*)  alloc((size_t)M_ROWS * D_ * 2);        // LN out (fp16 GEMM A)
    void*  s_big = alloc((size_t)M_ROWS * MLP_H_ * 2);            // qkv (f32) | mlp1 out (f16) | head1 partials
    f16*   s_flat   = s_h;                                        // alias (dead by then)
    float* s_hidden = s_out;                                      // alias (dead by then)
    float* s_qkv = (float*)s_big;
    f16*   s_m   = (f16*)s_big;
    float* s_part = (float*)s_big;

    dim3 blk(256);
    patch_embed_kernel<<<dim3(M_ROWS), blk, 0, stream>>>(x, cls, Wp, bp, s_out);

    for (int i = 0; i < 2; ++i) {
        const float* lw = ln_w + (size_t)i * T1_ * D_;
        const float* lb = ln_b + (size_t)i * T1_ * D_;
        ln_kernel<<<dim3(B_), blk, 0, stream>>>(s_out, lw, lb, s_h);
        gemm_kernel<0, float><<<dim3(768 / 128, M_ROWS / 128, 1), blk, 0, stream>>>(
            s_h, qkv_w + (size_t)i * D_ * 3 * D_, qkv_b + (size_t)i * 3 * D_,
            nullptr, s_qkv, M_ROWS, 768, D_);
        attn_kernel<<<dim3(B_ * H_), blk, 0, stream>>>(s_qkv, s_out, s_r);
        ln_kernel<<<dim3(B_), blk, 0, stream>>>(s_r, lw, lb, s_h);
        gemm_kernel<1, f16><<<dim3(MLP_H_ / 128, M_ROWS / 128, 1), blk, 0, stream>>>(
            s_h, mlp1_w + (size_t)i * D_ * MLP_H_, mlp1_b + (size_t)i * MLP_H_,
            nullptr, s_m, M_ROWS, MLP_H_, D_);
        gemm_kernel<2, float><<<dim3(D_ / 128, M_ROWS / 128, 1), blk, 0, stream>>>(
            s_m, mlp2_w + (size_t)i * MLP_H_ * D_, mlp2_b + (size_t)i * D_,
            s_r, s_out, M_ROWS, D_, MLP_H_);
    }

    cvt_kernel<<<dim3(1024), blk, 0, stream>>>(s_out, s_flat, M_ROWS * D_);
    // head1: M=256, N=8192, K=16640, split-K=4 -> 512 blocks
    gemm_kernel<4, float><<<dim3(HEAD_H_ / 128, 2, 4), blk, 0, stream>>>(
        s_flat, head1_w, nullptr, nullptr, s_part, 256, HEAD_H_, M_ROWS);
    combine_silu<<<dim3(B_ * HEAD_H_ / 256), blk, 0, stream>>>(s_part, head1_b, s_hidden);
    head2_kernel<<<dim3(B_), blk, 0, stream>>>(s_hidden, head2_w, head2_b, outp);
}

// Round 2
// 1375.585 us; speedup vs baseline: 1.0789x; 1.0789x over previous
//
#include <hip/hip_runtime.h>
#include <hip/hip_fp16.h>
#include <math.h>
#include <stdint.h>

#define B_ 256
#define C_ 3
#define IMG_ 32
#define D_ 256
#define H_ 8
#define HD_ 32
#define T1_ 65
#define MLP_H_ 2048
#define HEAD_H_ 8192
#define NCLS 10
#define PDIM 48
#define M_ROWS (B_*T1_)   // 16640

typedef _Float16 f16;
typedef _Float16 f16x8 __attribute__((ext_vector_type(8)));
typedef _Float16 f16x4 __attribute__((ext_vector_type(4)));
typedef float f32x4 __attribute__((ext_vector_type(4)));

typedef const void __attribute__((address_space(1))) glob_cv;
typedef void __attribute__((address_space(3))) lds_v;

__device__ __forceinline__ void async16(const void* g, void* l) {
    __builtin_amdgcn_global_load_lds((glob_cv*)g, (lds_v*)l, 16, 0, 0);
}

// ---------------- patch embed + cls + positional encoding ----------------
__global__ __launch_bounds__(256) void patch_embed_kernel(
        const float* __restrict__ x, const float* __restrict__ cls,
        const float* __restrict__ Wp, const float* __restrict__ bp,
        float* __restrict__ out) {
    int bt = blockIdx.x;
    int b = bt / T1_;
    int t = bt % T1_;
    int d = threadIdx.x;
    int i2 = d & ~1;
    float div = expf((float)i2 * (-9.210340371976184f / 256.0f));
    float ang = (float)t * div;
    float pe = (d & 1) ? cosf(ang) : sinf(ang);

    __shared__ float patch[PDIM];
    if (t > 0) {
        int p = t - 1;
        int py = p >> 3, px = p & 7;
        if (threadIdx.x < PDIM) {
            int j = threadIdx.x;
            int c = j >> 4, r = j & 15;
            int iy = r >> 2, ix = r & 3;
            patch[j] = x[((b * C_ + c) * IMG_ + py * 4 + iy) * IMG_ + px * 4 + ix];
        }
    }
    __syncthreads();
    float acc;
    if (t == 0) {
        acc = cls[d];
    } else {
        acc = bp[d];
        #pragma unroll
        for (int j = 0; j < PDIM; ++j) acc += patch[j] * Wp[j * D_ + d];
    }
    out[(size_t)bt * D_ + d] = acc + pe;
}

// ---------------- LayerNorm over (T1,D) per batch, write fp16 ----------------
__global__ __launch_bounds__(256) void ln_kernel(
        const float* __restrict__ xin, const float* __restrict__ w,
        const float* __restrict__ bb, f16* __restrict__ hout) {
    int b = blockIdx.x;
    const float* xb = xin + (size_t)b * (T1_ * D_);
    float s = 0.f, s2 = 0.f;
    for (int i = threadIdx.x; i < T1_ * D_; i += 256) {
        float v = xb[i]; s += v; s2 += v * v;
    }
    #pragma unroll
    for (int o = 32; o > 0; o >>= 1) { s += __shfl_down(s, o); s2 += __shfl_down(s2, o); }
    __shared__ float rs[4], rs2[4];
    __shared__ float mu_s, rstd_s;
    int wid = threadIdx.x >> 6;
    if ((threadIdx.x & 63) == 0) { rs[wid] = s; rs2[wid] = s2; }
    __syncthreads();
    if (threadIdx.x == 0) {
        float S = rs[0] + rs[1] + rs[2] + rs[3];
        float S2 = rs2[0] + rs2[1] + rs2[2] + rs2[3];
        const float inv_n = 1.0f / (float)(T1_ * D_);
        float mu = S * inv_n;
        float var = S2 * inv_n - mu * mu;
        mu_s = mu; rstd_s = rsqrtf(var + 1e-5f);
    }
    __syncthreads();
    float mu = mu_s, rstd = rstd_s;
    f16* hb = hout + (size_t)b * (T1_ * D_);
    for (int i = threadIdx.x; i < T1_ * D_; i += 256) {
        float v = (xb[i] - mu) * rstd * w[i] + bb[i];
        hb[i] = (f16)v;
    }
}

// ---------------- weight transpose+convert: W[K][N] f32 -> Wt[N][K] f16 -------
__global__ __launch_bounds__(256) void transpose_cvt(
        const float* __restrict__ W, f16* __restrict__ Wt, int K, int N) {
    __shared__ float L[32][33];
    int n0 = blockIdx.x * 32, k0 = blockIdx.y * 32;
    int t = threadIdx.x;
    int r = t >> 3, c4 = (t & 7) * 4;
    const float4 v = *(const float4*)(W + (size_t)(k0 + r) * N + n0 + c4);
    L[r][c4] = v.x; L[r][c4 + 1] = v.y; L[r][c4 + 2] = v.z; L[r][c4 + 3] = v.w;
    __syncthreads();
    f16x4 h;
    h[0] = (f16)L[c4][r]; h[1] = (f16)L[c4 + 1][r];
    h[2] = (f16)L[c4 + 2][r]; h[3] = (f16)L[c4 + 3][r];
    *(f16x4*)(Wt + (size_t)(n0 + r) * K + k0 + c4) = h;
}

// ---------------- fast f16 GEMM (m97 style): C = A[M][K] * Bt[N][K]^T ---------
// EPI: 0 = +bias (f32 out), 1 = +bias,relu (f16 out), 2 = +bias+residual (f32 out)
template<int EPI, typename OutT>
__global__ __launch_bounds__(256) void gemm_f16(
        const f16* __restrict__ A, const f16* __restrict__ Bt,
        const float* __restrict__ bias, const float* __restrict__ Res,
        OutT* __restrict__ Cc, int M, int N, int K) {
    __shared__ __align__(16) f16 As[128 * 32];
    __shared__ __align__(16) f16 Bs[128 * 32];
    int nb = blockIdx.x, mb = blockIdx.y;
    int t = threadIdx.x;
    int lane = t & 63, wid = t >> 6;
    int wr = wid >> 1, wc = wid & 1;
    int lr = lane & 15, kq = lane >> 4;
    int row0 = mb * 128, col0 = nb * 128;

    f32x4 acc[4][4];
    #pragma unroll
    for (int mi = 0; mi < 4; ++mi)
        #pragma unroll
        for (int ni = 0; ni < 4; ++ni)
            #pragma unroll
            for (int r = 0; r < 4; ++r) acc[mi][ni][r] = 0.f;

    int sr = t >> 2;            // 0..63
    int k8 = (t & 3) * 8;
    const f16* Ab = A + (size_t)row0 * K + k8;
    const f16* Bb = Bt + (size_t)col0 * K + k8;

    for (int k0 = 0; k0 < K; k0 += 32) {
        __syncthreads();
        async16(Ab + (size_t)sr * K + k0,        &As[t * 8]);
        async16(Ab + (size_t)(sr + 64) * K + k0, &As[2048 + t * 8]);
        async16(Bb + (size_t)sr * K + k0,        &Bs[t * 8]);
        async16(Bb + (size_t)(sr + 64) * K + k0, &Bs[2048 + t * 8]);
        __syncthreads();
        f16x8 af[4], bf[4];
        #pragma unroll
        for (int mi = 0; mi < 4; ++mi)
            af[mi] = *(const f16x8*)&As[(wr * 64 + mi * 16 + lr) * 32 + kq * 8];
        #pragma unroll
        for (int ni = 0; ni < 4; ++ni)
            bf[ni] = *(const f16x8*)&Bs[(wc * 64 + ni * 16 + lr) * 32 + kq * 8];
        #pragma unroll
        for (int mi = 0; mi < 4; ++mi)
            #pragma unroll
            for (int ni = 0; ni < 4; ++ni)
                acc[mi][ni] = __builtin_amdgcn_mfma_f32_16x16x32_f16(af[mi], bf[ni], acc[mi][ni], 0, 0, 0);
    }

    #pragma unroll
    for (int mi = 0; mi < 4; ++mi) {
        #pragma unroll
        for (int ni = 0; ni < 4; ++ni) {
            int col = col0 + wc * 64 + ni * 16 + lr;
            #pragma unroll
            for (int r = 0; r < 4; ++r) {
                int row = row0 + wr * 64 + mi * 16 + kq * 4 + r;
                float v = acc[mi][ni][r] + bias[col];
                if (EPI == 1) v = fmaxf(v, 0.f);
                if (EPI == 2) v += Res[(size_t)row * N + col];
                Cc[(size_t)row * N + col] = (OutT)v;
            }
        }
    }
}

// ---------------- head1 GEMM: A f16 [256][16640], B f32 [16640][8192] ---------
// BM=256 (all M), BN=64, split-K=4 -> B read exactly once.
__global__ __launch_bounds__(256) void gemm_head1(
        const f16* __restrict__ A, const float* __restrict__ Bw,
        float* __restrict__ Cp) {
    __shared__ __align__(16) f16 As[256 * 32];
    __shared__ __align__(16) float Bs[32 * 64];
    const int K = M_ROWS, N = HEAD_H_;
    int nb = blockIdx.x;     // 0..127
    int z = blockIdx.y;      // 0..3
    int t = threadIdx.x;
    int lane = t & 63, wid = t >> 6;
    int lr = lane & 15, kq = lane >> 4;
    int col0 = nb * 64;
    int kstart = z * (K / 4);

    f32x4 acc[4][4];
    #pragma unroll
    for (int mi = 0; mi < 4; ++mi)
        #pragma unroll
        for (int ni = 0; ni < 4; ++ni)
            #pragma unroll
            for (int r = 0; r < 4; ++r) acc[mi][ni][r] = 0.f;

    int sr = t >> 2;
    int k8 = (t & 3) * 8;
    const f16* Ab = A + k8;
    int bkr = t >> 4;            // 0..15
    int bnc = (t & 15) * 4;
    const float* Bb = Bw + col0 + bnc;

    for (int k0 = kstart; k0 < kstart + K / 4; k0 += 32) {
        __syncthreads();
        #pragma unroll
        for (int r = 0; r < 4; ++r)
            async16(Ab + (size_t)(sr + r * 64) * K + k0, &As[r * 2048 + t * 8]);
        async16(Bb + (size_t)(k0 + bkr) * N,      &Bs[t * 4]);
        async16(Bb + (size_t)(k0 + 16 + bkr) * N, &Bs[1024 + t * 4]);
        __syncthreads();
        f16x8 af[4];
        #pragma unroll
        for (int mi = 0; mi < 4; ++mi)
            af[mi] = *(const f16x8*)&As[(wid * 64 + mi * 16 + lr) * 32 + kq * 8];
        #pragma unroll
        for (int ni = 0; ni < 4; ++ni) {
            f16x8 bf;
            #pragma unroll
            for (int j = 0; j < 8; ++j) bf[j] = (f16)Bs[(kq * 8 + j) * 64 + ni * 16 + lr];
            #pragma unroll
            for (int mi = 0; mi < 4; ++mi)
                acc[mi][ni] = __builtin_amdgcn_mfma_f32_16x16x32_f16(af[mi], bf, acc[mi][ni], 0, 0, 0);
        }
    }

    float* Cout = Cp + (size_t)z * 256 * N;
    #pragma unroll
    for (int mi = 0; mi < 4; ++mi) {
        #pragma unroll
        for (int ni = 0; ni < 4; ++ni) {
            int col = col0 + ni * 16 + lr;
            #pragma unroll
            for (int r = 0; r < 4; ++r) {
                int row = wid * 64 + mi * 16 + kq * 4 + r;
                Cout[(size_t)row * N + col] = acc[mi][ni][r];
            }
        }
    }
}

// ---------------- attention (fp32), one block per (b,h) ----------------
__global__ __launch_bounds__(256) void attn_kernel(
        const float* __restrict__ qkv, const float* __restrict__ outres,
        float* __restrict__ r) {
    int bh = blockIdx.x;
    int b = bh >> 3, h = bh & 7;
    __shared__ float q[T1_][HD_], k[T1_][HD_], v[T1_][HD_];
    __shared__ float s[T1_][T1_ + 1];
    const float* base = qkv + (size_t)b * T1_ * 768 + h * 96;
    for (int idx = threadIdx.x; idx < T1_ * 96; idx += 256) {
        int t = idx / 96, rem = idx % 96;
        int j = rem >> 5, d = rem & 31;
        float val = base[(size_t)t * 768 + rem];
        if (j == 0) q[t][d] = val; else if (j == 1) k[t][d] = val; else v[t][d] = val;
    }
    __syncthreads();
    const float scale = 0.17677669529663687f;
    for (int idx = threadIdx.x; idx < T1_ * T1_; idx += 256) {
        int qt = idx / T1_, kt = idx % T1_;
        float acc = 0.f;
        #pragma unroll
        for (int d = 0; d < HD_; ++d) acc += q[qt][d] * k[kt][d];
        s[qt][kt] = acc * scale;
    }
    __syncthreads();
    if (threadIdx.x < T1_) {
        int qt = threadIdx.x;
        float m = -1e30f;
        for (int kt = 0; kt < T1_; ++kt) m = fmaxf(m, s[qt][kt]);
        float sum = 0.f;
        for (int kt = 0; kt < T1_; ++kt) { float e = __expf(s[qt][kt] - m); s[qt][kt] = e; sum += e; }
        float inv = 1.f / sum;
        for (int kt = 0; kt < T1_; ++kt) s[qt][kt] *= inv;
    }
    __syncthreads();
    for (int idx = threadIdx.x; idx < T1_ * HD_; idx += 256) {
        int t = idx >> 5, d = idx & 31;
        float acc = 0.f;
        for (int kt = 0; kt < T1_; ++kt) acc += s[t][kt] * v[kt][d];
        size_t o = (size_t)(b * T1_ + t) * D_ + h * HD_ + d;
        r[o] = acc + outres[o];
    }
}

// ---------------- fp32 -> fp16 convert ----------------
__global__ __launch_bounds__(256) void cvt_kernel(const float* __restrict__ in,
                                                  f16* __restrict__ o, int n) {
    int i = blockIdx.x * 256 + threadIdx.x;
    int stride = gridDim.x * 256;
    for (; i < n; i += stride) o[i] = (f16)in[i];
}

// ---------------- split-K combine + bias + silu ----------------
__global__ __launch_bounds__(256) void combine_silu(const float* __restrict__ part,
                                                    const float* __restrict__ bias,
                                                    float* __restrict__ o) {
    int idx = blockIdx.x * 256 + threadIdx.x;
    const int NP = 256 * HEAD_H_;
    float v = part[idx] + part[idx + NP] + part[idx + 2 * NP] + part[idx + 3 * NP]
            + bias[idx & (HEAD_H_ - 1)];
    o[idx] = v / (1.f + expf(-v));
}

// ---------------- head2 ----------------
__global__ __launch_bounds__(256) void head2_kernel(
        const float* __restrict__ hidden, const float* __restrict__ w,
        const float* __restrict__ bias, float* __restrict__ out) {
    int b = blockIdx.x;
    const float* hb = hidden + (size_t)b * HEAD_H_;
    float acc[NCLS];
    #pragma unroll
    for (int n = 0; n < NCLS; ++n) acc[n] = 0.f;
    for (int kk = threadIdx.x; kk < HEAD_H_; kk += 256) {
        float hv = hb[kk];
        const float* wr = w + (size_t)kk * NCLS;
        #pragma unroll
        for (int n = 0; n < NCLS; ++n) acc[n] += hv * wr[n];
    }
    #pragma unroll
    for (int n = 0; n < NCLS; ++n)
        #pragma unroll
        for (int o = 32; o > 0; o >>= 1) acc[n] += __shfl_down(acc[n], o);
    __shared__ float red[4][NCLS];
    int wid = threadIdx.x >> 6;
    if ((threadIdx.x & 63) == 0)
        for (int n = 0; n < NCLS; ++n) red[wid][n] = acc[n];
    __syncthreads();
    if (threadIdx.x < NCLS) {
        int n = threadIdx.x;
        out[(size_t)b * NCLS + n] = red[0][n] + red[1][n] + red[2][n] + red[3][n] + bias[n];
    }
}

extern "C" void kernel_launch(void* const* d_in, const int* in_sizes, int n_in,
                              void* d_out, int out_size, void* d_ws, size_t ws_size,
                              hipStream_t stream) {
    (void)in_sizes; (void)n_in; (void)out_size; (void)ws_size;
    const float* x       = (const float*)d_in[0];
    const float* cls     = (const float*)d_in[1];
    const float* Wp      = (const float*)d_in[2];
    const float* bp      = (const float*)d_in[3];
    const float* qkv_w   = (const float*)d_in[4];
    const float* qkv_b   = (const float*)d_in[5];
    const float* ln_w    = (const float*)d_in[6];
    const float* ln_b    = (const float*)d_in[7];
    const float* mlp1_w  = (const float*)d_in[8];
    const float* mlp1_b  = (const float*)d_in[9];
    const float* mlp2_w  = (const float*)d_in[10];
    const float* mlp2_b  = (const float*)d_in[11];
    const float* head1_w = (const float*)d_in[12];
    const float* head1_b = (const float*)d_in[13];
    const float* head2_w = (const float*)d_in[14];
    const float* head2_b = (const float*)d_in[15];
    float* outp = (float*)d_out;

    char* ws = (char*)d_ws;
    size_t off = 0;
    auto alloc = [&](size_t bytes) -> void* {
        void* p = ws + off; off += (bytes + 255) & ~(size_t)255; return p;
    };
    float* s_out = (float*)alloc((size_t)M_ROWS * D_ * 4);
    float* s_r   = (float*)alloc((size_t)M_ROWS * D_ * 4);
    f16*   s_h   = (f16*)  alloc((size_t)M_ROWS * D_ * 2);
    void*  s_big = alloc((size_t)M_ROWS * MLP_H_ * 2);
    f16*   w_qkv_t  = (f16*)alloc((size_t)2 * 768 * 256 * 2);
    f16*   w_mlp1_t = (f16*)alloc((size_t)2 * 2048 * 256 * 2);
    f16*   w_mlp2_t = (f16*)alloc((size_t)2 * 256 * 2048 * 2);
    f16*   s_flat   = s_h;
    float* s_hidden = s_out;
    float* s_qkv = (float*)s_big;
    f16*   s_m   = (f16*)s_big;
    float* s_part = (float*)s_big;

    dim3 blk(256);

    // weight pre-transpose/convert (f32 [K][N] -> f16 [N][K])
    for (int i = 0; i < 2; ++i) {
        transpose_cvt<<<dim3(768 / 32, 256 / 32), blk, 0, stream>>>(
            qkv_w + (size_t)i * D_ * 768, w_qkv_t + (size_t)i * 768 * 256, 256, 768);
        transpose_cvt<<<dim3(2048 / 32, 256 / 32), blk, 0, stream>>>(
            mlp1_w + (size_t)i * D_ * 2048, w_mlp1_t + (size_t)i * 2048 * 256, 256, 2048);
        transpose_cvt<<<dim3(256 / 32, 2048 / 32), blk, 0, stream>>>(
            mlp2_w + (size_t)i * 2048 * 256, w_mlp2_t + (size_t)i * 256 * 2048, 2048, 256);
    }

    patch_embed_kernel<<<dim3(M_ROWS), blk, 0, stream>>>(x, cls, Wp, bp, s_out);

    for (int i = 0; i < 2; ++i) {
        const float* lw = ln_w + (size_t)i * T1_ * D_;
        const float* lb = ln_b + (size_t)i * T1_ * D_;
        ln_kernel<<<dim3(B_), blk, 0, stream>>>(s_out, lw, lb, s_h);
        gemm_f16<0, float><<<dim3(768 / 128, M_ROWS / 128), blk, 0, stream>>>(
            s_h, w_qkv_t + (size_t)i * 768 * 256, qkv_b + (size_t)i * 768,
            nullptr, s_qkv, M_ROWS, 768, 256);
        attn_kernel<<<dim3(B_ * H_), blk, 0, stream>>>(s_qkv, s_out, s_r);
        ln_kernel<<<dim3(B_), blk, 0, stream>>>(s_r, lw, lb, s_h);
        gemm_f16<1, f16><<<dim3(MLP_H_ / 128, M_ROWS / 128), blk, 0, stream>>>(
            s_h, w_mlp1_t + (size_t)i * 2048 * 256, mlp1_b + (size_t)i * MLP_H_,
            nullptr, s_m, M_ROWS, MLP_H_, 256);
        gemm_f16<2, float><<<dim3(D_ / 128, M_ROWS / 128), blk, 0, stream>>>(
            s_m, w_mlp2_t + (size_t)i * 256 * 2048, mlp2_b + (size_t)i * D_,
            s_r, s_out, M_ROWS, D_, MLP_H_);
    }

    cvt_kernel<<<dim3(1024), blk, 0, stream>>>(s_out, s_flat, M_ROWS * D_);
    gemm_head1<<<dim3(HEAD_H_ / 64, 4), blk, 0, stream>>>(s_flat, head1_w, s_part);
    combine_silu<<<dim3(B_ * HEAD_H_ / 256), blk, 0, stream>>>(s_part, head1_b, s_hidden);
    head2_kernel<<<dim3(B_), blk, 0, stream>>>(s_hidden, head2_w, head2_b, outp);
}

// Round 3
// 1169.181 us; speedup vs baseline: 1.2694x; 1.1765x over previous
//
#include <hip/hip_runtime.h>
#include <hip/hip_fp16.h>
#include <math.h>
#include <stdint.h>

#define B_ 256
#define C_ 3
#define IMG_ 32
#define D_ 256
#define H_ 8
#define HD_ 32
#define T1_ 65
#define MLP_H_ 2048
#define HEAD_H_ 8192
#define NCLS 10
#define PDIM 48
#define M_ROWS (B_*T1_)   // 16640

typedef _Float16 f16;
typedef _Float16 f16x8 __attribute__((ext_vector_type(8)));
typedef _Float16 f16x4 __attribute__((ext_vector_type(4)));
typedef float f32x4 __attribute__((ext_vector_type(4)));

typedef const void __attribute__((address_space(1))) glob_cv;
typedef void __attribute__((address_space(3))) lds_v;

__device__ __forceinline__ void async16(const void* g, void* l) {
    __builtin_amdgcn_global_load_lds((glob_cv*)g, (lds_v*)l, 16, 0, 0);
}

// ---------------- WpT build: Wp f32 [48][256] -> WpT f16 [256][64] (j-pad 0) --
__global__ __launch_bounds__(256) void wpt_build(const float* __restrict__ Wp,
                                                 f16* __restrict__ WpT) {
    int idx = blockIdx.x * 256 + threadIdx.x;   // 256*64
    int d = idx >> 6, j = idx & 63;
    WpT[idx] = (j < PDIM) ? (f16)Wp[j * D_ + d] : (f16)0.f;
}

// ---------------- patch embed via MFMA + cls + positional encoding ------------
__global__ __launch_bounds__(256) void patch_mfma(
        const float* __restrict__ x, const float* __restrict__ cls,
        const f16* __restrict__ WpT, const float* __restrict__ bp,
        float* __restrict__ out) {
    int b = blockIdx.x;
    __shared__ float xs[3072];
    __shared__ __align__(16) f16 Ap[64 * 64];
    __shared__ __align__(16) f16 Bp[256 * 64];
    int tid = threadIdx.x;
    int lane = tid & 63, wid = tid >> 6;
    int lr = lane & 15, kq = lane >> 4;

    for (int i = tid; i < 768; i += 256)
        ((float4*)xs)[i] = ((const float4*)(x + (size_t)b * 3072))[i];
    for (int i = tid; i < 2048; i += 256)
        async16(WpT + (size_t)i * 8, &Bp[i * 8]);
    __syncthreads();
    for (int i = tid; i < 64 * 64; i += 256) {
        int t = i >> 6, j = i & 63;
        float val = 0.f;
        if (j < PDIM) {
            int py = t >> 3, px = t & 7;
            int c = j >> 4, rr = j & 15;
            int iy = rr >> 2, ix = rr & 3;
            val = xs[c * 1024 + (py * 4 + iy) * 32 + px * 4 + ix];
        }
        Ap[i] = (f16)val;
    }
    __syncthreads();

    for (int tile = wid; tile < 64; tile += 4) {
        int mi = tile >> 4, ni = tile & 15;
        f32x4 acc = {0.f, 0.f, 0.f, 0.f};
        #pragma unroll
        for (int ks = 0; ks < 2; ++ks) {
            f16x8 a = *(const f16x8*)&Ap[(mi * 16 + lr) * 64 + ks * 32 + kq * 8];
            f16x8 bb = *(const f16x8*)&Bp[(ni * 16 + lr) * 64 + ks * 32 + kq * 8];
            acc = __builtin_amdgcn_mfma_f32_16x16x32_f16(a, bb, acc, 0, 0, 0);
        }
        int d = ni * 16 + lr;
        float div = __expf((float)(d & ~1) * (-9.210340371976184f / 256.0f));
        #pragma unroll
        for (int r = 0; r < 4; ++r) {
            int t = 1 + mi * 16 + kq * 4 + r;
            float ang = (float)t * div;
            float pe = (d & 1) ? __cosf(ang) : __sinf(ang);
            out[((size_t)b * T1_ + t) * D_ + d] = acc[r] + bp[d] + pe;
        }
    }
    // row 0: cls + pe(0,d);  pe(0,even)=sin0=0, pe(0,odd)=cos0=1
    out[(size_t)b * T1_ * D_ + tid] = cls[tid] + ((tid & 1) ? 1.f : 0.f);
}

// ---------------- LayerNorm over (T1,D) per batch, 1024 thr, write fp16 ------
__global__ __launch_bounds__(1024) void ln_kernel(
        const float* __restrict__ xin, const float* __restrict__ w,
        const float* __restrict__ bb, f16* __restrict__ hout) {
    int b = blockIdx.x;
    const float4* x4 = (const float4*)(xin + (size_t)b * (T1_ * D_));
    const float4* w4 = (const float4*)w;
    const float4* b4 = (const float4*)bb;
    int tid = threadIdx.x;
    float s = 0.f, s2 = 0.f;
    for (int i = tid; i < 4160; i += 1024) {
        float4 v = x4[i];
        s  += v.x + v.y + v.z + v.w;
        s2 += v.x * v.x + v.y * v.y + v.z * v.z + v.w * v.w;
    }
    #pragma unroll
    for (int o = 32; o > 0; o >>= 1) { s += __shfl_down(s, o); s2 += __shfl_down(s2, o); }
    __shared__ float rs[16], rs2[16];
    __shared__ float mu_s, rstd_s;
    int wid = tid >> 6;
    if ((tid & 63) == 0) { rs[wid] = s; rs2[wid] = s2; }
    __syncthreads();
    if (tid == 0) {
        float S = 0.f, S2 = 0.f;
        #pragma unroll
        for (int i = 0; i < 16; ++i) { S += rs[i]; S2 += rs2[i]; }
        const float inv_n = 1.0f / (float)(T1_ * D_);
        float mu = S * inv_n;
        float var = S2 * inv_n - mu * mu;
        mu_s = mu; rstd_s = rsqrtf(var + 1e-5f);
    }
    __syncthreads();
    float mu = mu_s, rstd = rstd_s;
    f16* hb = hout + (size_t)b * (T1_ * D_);
    for (int i = tid; i < 4160; i += 1024) {
        float4 v = x4[i]; float4 wv = w4[i]; float4 bv = b4[i];
        f16x4 h;
        h[0] = (f16)((v.x - mu) * rstd * wv.x + bv.x);
        h[1] = (f16)((v.y - mu) * rstd * wv.y + bv.y);
        h[2] = (f16)((v.z - mu) * rstd * wv.z + bv.z);
        h[3] = (f16)((v.w - mu) * rstd * wv.w + bv.w);
        *(f16x4*)(hb + i * 4) = h;
    }
}

// ---------------- weight transpose+convert: W[K][N] f32 -> Wt[N][K] f16 -------
__global__ __launch_bounds__(256) void transpose_cvt(
        const float* __restrict__ W, f16* __restrict__ Wt, int K, int N) {
    __shared__ float L[32][33];
    int n0 = blockIdx.x * 32, k0 = blockIdx.y * 32;
    int t = threadIdx.x;
    int r = t >> 3, c4 = (t & 7) * 4;
    const float4 v = *(const float4*)(W + (size_t)(k0 + r) * N + n0 + c4);
    L[r][c4] = v.x; L[r][c4 + 1] = v.y; L[r][c4 + 2] = v.z; L[r][c4 + 3] = v.w;
    __syncthreads();
    f16x4 h;
    h[0] = (f16)L[c4][r]; h[1] = (f16)L[c4 + 1][r];
    h[2] = (f16)L[c4 + 2][r]; h[3] = (f16)L[c4 + 3][r];
    *(f16x4*)(Wt + (size_t)(n0 + r) * K + k0 + c4) = h;
}

// ---------------- fast f16 GEMM: C = A[M][K] * Bt[N][K]^T ---------------------
// EPI: 0=+bias, 1=+bias,relu, 2=+bias+residual, 3=+bias+residual dual f32/f16
template<int EPI, typename OutT>
__global__ __launch_bounds__(256) void gemm_f16(
        const f16* __restrict__ A, const f16* __restrict__ Bt,
        const float* __restrict__ bias, const float* __restrict__ Res,
        OutT* __restrict__ Cc, f16* __restrict__ C2, int M, int N, int K) {
    __shared__ __align__(16) f16 As[128 * 32];
    __shared__ __align__(16) f16 Bs[128 * 32];
    int nb = blockIdx.x, mb = blockIdx.y;
    int t = threadIdx.x;
    int lane = t & 63, wid = t >> 6;
    int wr = wid >> 1, wc = wid & 1;
    int lr = lane & 15, kq = lane >> 4;
    int row0 = mb * 128, col0 = nb * 128;

    f32x4 acc[4][4];
    #pragma unroll
    for (int mi = 0; mi < 4; ++mi)
        #pragma unroll
        for (int ni = 0; ni < 4; ++ni)
            #pragma unroll
            for (int r = 0; r < 4; ++r) acc[mi][ni][r] = 0.f;

    int sr = t >> 2;
    int k8 = (t & 3) * 8;
    const f16* Ab = A + (size_t)row0 * K + k8;
    const f16* Bb = Bt + (size_t)col0 * K + k8;

    for (int k0 = 0; k0 < K; k0 += 32) {
        __syncthreads();
        async16(Ab + (size_t)sr * K + k0,        &As[t * 8]);
        async16(Ab + (size_t)(sr + 64) * K + k0, &As[2048 + t * 8]);
        async16(Bb + (size_t)sr * K + k0,        &Bs[t * 8]);
        async16(Bb + (size_t)(sr + 64) * K + k0, &Bs[2048 + t * 8]);
        __syncthreads();
        f16x8 af[4], bf[4];
        #pragma unroll
        for (int mi = 0; mi < 4; ++mi)
            af[mi] = *(const f16x8*)&As[(wr * 64 + mi * 16 + lr) * 32 + kq * 8];
        #pragma unroll
        for (int ni = 0; ni < 4; ++ni)
            bf[ni] = *(const f16x8*)&Bs[(wc * 64 + ni * 16 + lr) * 32 + kq * 8];
        #pragma unroll
        for (int mi = 0; mi < 4; ++mi)
            #pragma unroll
            for (int ni = 0; ni < 4; ++ni)
                acc[mi][ni] = __builtin_amdgcn_mfma_f32_16x16x32_f16(af[mi], bf[ni], acc[mi][ni], 0, 0, 0);
    }

    #pragma unroll
    for (int mi = 0; mi < 4; ++mi) {
        #pragma unroll
        for (int ni = 0; ni < 4; ++ni) {
            int col = col0 + wc * 64 + ni * 16 + lr;
            #pragma unroll
            for (int r = 0; r < 4; ++r) {
                int row = row0 + wr * 64 + mi * 16 + kq * 4 + r;
                float v = acc[mi][ni][r] + bias[col];
                if (EPI == 1) v = fmaxf(v, 0.f);
                if (EPI == 2 || EPI == 3) v += Res[(size_t)row * N + col];
                Cc[(size_t)row * N + col] = (OutT)v;
                if (EPI == 3) C2[(size_t)row * N + col] = (f16)v;
            }
        }
    }
}

// ---------------- head1 GEMM: A f16 [256][16640], B f32 [16640][8192] ---------
__global__ __launch_bounds__(256) void gemm_head1(
        const f16* __restrict__ A, const float* __restrict__ Bw,
        float* __restrict__ Cp) {
    __shared__ __align__(16) f16 As[256 * 32];
    __shared__ __align__(16) float Bs[32 * 64];
    const int K = M_ROWS, N = HEAD_H_;
    int nb = blockIdx.x;
    int z = blockIdx.y;
    int t = threadIdx.x;
    int lane = t & 63, wid = t >> 6;
    int lr = lane & 15, kq = lane >> 4;
    int col0 = nb * 64;
    int kstart = z * (K / 4);

    f32x4 acc[4][4];
    #pragma unroll
    for (int mi = 0; mi < 4; ++mi)
        #pragma unroll
        for (int ni = 0; ni < 4; ++ni)
            #pragma unroll
            for (int r = 0; r < 4; ++r) acc[mi][ni][r] = 0.f;

    int sr = t >> 2;
    int k8 = (t & 3) * 8;
    const f16* Ab = A + k8;
    int bkr = t >> 4;
    int bnc = (t & 15) * 4;
    const float* Bb = Bw + col0 + bnc;

    for (int k0 = kstart; k0 < kstart + K / 4; k0 += 32) {
        __syncthreads();
        #pragma unroll
        for (int r = 0; r < 4; ++r)
            async16(Ab + (size_t)(sr + r * 64) * K + k0, &As[r * 2048 + t * 8]);
        async16(Bb + (size_t)(k0 + bkr) * N,      &Bs[t * 4]);
        async16(Bb + (size_t)(k0 + 16 + bkr) * N, &Bs[1024 + t * 4]);
        __syncthreads();
        f16x8 af[4];
        #pragma unroll
        for (int mi = 0; mi < 4; ++mi)
            af[mi] = *(const f16x8*)&As[(wid * 64 + mi * 16 + lr) * 32 + kq * 8];
        #pragma unroll
        for (int ni = 0; ni < 4; ++ni) {
            f16x8 bf;
            #pragma unroll
            for (int j = 0; j < 8; ++j) bf[j] = (f16)Bs[(kq * 8 + j) * 64 + ni * 16 + lr];
            #pragma unroll
            for (int mi = 0; mi < 4; ++mi)
                acc[mi][ni] = __builtin_amdgcn_mfma_f32_16x16x32_f16(af[mi], bf, acc[mi][ni], 0, 0, 0);
        }
    }

    float* Cout = Cp + (size_t)z * 256 * N;
    #pragma unroll
    for (int mi = 0; mi < 4; ++mi) {
        #pragma unroll
        for (int ni = 0; ni < 4; ++ni) {
            int col = col0 + ni * 16 + lr;
            #pragma unroll
            for (int r = 0; r < 4; ++r) {
                int row = wid * 64 + mi * 16 + kq * 4 + r;
                Cout[(size_t)row * N + col] = acc[mi][ni][r];
            }
        }
    }
}

// ---------------- MFMA attention, one block per (b,h) -------------------------
__global__ __launch_bounds__(256) void attn_kernel(
        const f16* __restrict__ qkv, const float* __restrict__ outres,
        float* __restrict__ r) {
    int b = blockIdx.x >> 3, h = blockIdx.x & 7;
    __shared__ __align__(16) f16 Qs[80 * 32];
    __shared__ __align__(16) f16 Ks[80 * 32];
    __shared__ __align__(16) f16 Vt[32 * 96];
    __shared__ float Sf[80 * 81];
    __shared__ __align__(16) f16 Pf[80 * 96];
    int tid = threadIdx.x;
    int lane = tid & 63, wid = tid >> 6;
    int lr = lane & 15, kq = lane >> 4;
    const float scale = 0.17677669529663687f;   // 1/sqrt(32)

    const f16* base = qkv + (size_t)b * T1_ * 768 + h * 96;
    for (int i = tid; i < T1_ * 12; i += 256) {
        int t = i / 12, c = i % 12;
        f16x8 vv = *(const f16x8*)(base + (size_t)t * 768 + c * 8);
        if (c < 4) {
            f16x8 q8;
            #pragma unroll
            for (int j = 0; j < 8; ++j) q8[j] = (f16)((float)vv[j] * scale);
            *(f16x8*)&Qs[t * 32 + c * 8] = q8;
        } else if (c < 8) {
            *(f16x8*)&Ks[t * 32 + (c - 4) * 8] = vv;
        } else {
            int d0 = (c - 8) * 8;
            #pragma unroll
            for (int j = 0; j < 8; ++j) Vt[(d0 + j) * 96 + t] = vv[j];
        }
    }
    for (int i = tid; i < 32 * 31; i += 256) {   // zero Vt pad cols 65..95
        int d = i / 31, kt = 65 + i % 31;
        Vt[d * 96 + kt] = (f16)0.f;
    }
    __syncthreads();

    // QK^T: 25 tiles of 16x16, K=32 (one MFMA step)
    for (int tile = wid; tile < 25; tile += 4) {
        int mi = tile / 5, ni = tile % 5;
        f16x8 a = *(const f16x8*)&Qs[(mi * 16 + lr) * 32 + kq * 8];
        f16x8 bb = *(const f16x8*)&Ks[(ni * 16 + lr) * 32 + kq * 8];
        f32x4 c = {0.f, 0.f, 0.f, 0.f};
        c = __builtin_amdgcn_mfma_f32_16x16x32_f16(a, bb, c, 0, 0, 0);
        #pragma unroll
        for (int rr2 = 0; rr2 < 4; ++rr2)
            Sf[(mi * 16 + kq * 4 + rr2) * 81 + ni * 16 + lr] = c[rr2];
    }
    __syncthreads();

    // softmax: 4 lanes per row
    for (int row = tid >> 2; row < T1_; row += 64) {
        int sub = tid & 3;
        float m = -1e30f;
        for (int kt = sub; kt < T1_; kt += 4) m = fmaxf(m, Sf[row * 81 + kt]);
        m = fmaxf(m, __shfl_xor(m, 1));
        m = fmaxf(m, __shfl_xor(m, 2));
        float sum = 0.f;
        for (int kt = sub; kt < T1_; kt += 4) {
            float e = __expf(Sf[row * 81 + kt] - m);
            Sf[row * 81 + kt] = e; sum += e;
        }
        sum += __shfl_xor(sum, 1);
        sum += __shfl_xor(sum, 2);
        float inv = 1.f / sum;
        for (int kt = sub; kt < T1_; kt += 4)
            Pf[row * 96 + kt] = (f16)(Sf[row * 81 + kt] * inv);
        for (int kt = T1_ + sub; kt < 96; kt += 4)
            Pf[row * 96 + kt] = (f16)0.f;
    }
    __syncthreads();

    // PV: 10 tiles (5 m x 2 n), K=96 (3 MFMA steps)
    for (int tile = wid; tile < 10; tile += 4) {
        int mi = tile >> 1, ni = tile & 1;
        f32x4 acc = {0.f, 0.f, 0.f, 0.f};
        #pragma unroll
        for (int ks = 0; ks < 3; ++ks) {
            f16x8 a = *(const f16x8*)&Pf[(mi * 16 + lr) * 96 + ks * 32 + kq * 8];
            f16x8 bv = *(const f16x8*)&Vt[(ni * 16 + lr) * 96 + ks * 32 + kq * 8];
            acc = __builtin_amdgcn_mfma_f32_16x16x32_f16(a, bv, acc, 0, 0, 0);
        }
        #pragma unroll
        for (int rr2 = 0; rr2 < 4; ++rr2) {
            int qt = mi * 16 + kq * 4 + rr2;
            if (qt < T1_) {
                size_t o = ((size_t)b * T1_ + qt) * D_ + h * HD_ + ni * 16 + lr;
                r[o] = acc[rr2] + outres[o];
            }
        }
    }
}

// ---------------- head2 fused: split-K combine + bias + silu + matvec ---------
__global__ __launch_bounds__(256) void head2_fused(
        const float* __restrict__ part, const float* __restrict__ h1b,
        const float* __restrict__ w, const float* __restrict__ h2b,
        float* __restrict__ out) {
    int b = blockIdx.x;
    const int NP = 256 * HEAD_H_;
    int tid = threadIdx.x;
    float acc[NCLS];
    #pragma unroll
    for (int n = 0; n < NCLS; ++n) acc[n] = 0.f;
    for (int kk = tid; kk < HEAD_H_; kk += 256) {
        size_t o = (size_t)b * HEAD_H_ + kk;
        float v = part[o] + part[o + NP] + part[o + 2 * (size_t)NP] + part[o + 3 * (size_t)NP]
                + h1b[kk];
        v = v / (1.f + __expf(-v));
        const float* wr = w + (size_t)kk * NCLS;
        #pragma unroll
        for (int n = 0; n < NCLS; ++n) acc[n] += v * wr[n];
    }
    #pragma unroll
    for (int n = 0; n < NCLS; ++n)
        #pragma unroll
        for (int o = 32; o > 0; o >>= 1) acc[n] += __shfl_down(acc[n], o);
    __shared__ float red[4][NCLS];
    int wid = tid >> 6;
    if ((tid & 63) == 0)
        for (int n = 0; n < NCLS; ++n) red[wid][n] = acc[n];
    __syncthreads();
    if (tid < NCLS) {
        int n = tid;
        out[(size_t)b * NCLS + n] = red[0][n] + red[1][n] + red[2][n] + red[3][n] + h2b[n];
    }
}

extern "C" void kernel_launch(void* const* d_in, const int* in_sizes, int n_in,
                              void* d_out, int out_size, void* d_ws, size_t ws_size,
                              hipStream_t stream) {
    (void)in_sizes; (void)n_in; (void)out_size; (void)ws_size;
    const float* x       = (const float*)d_in[0];
    const float* cls     = (const float*)d_in[1];
    const float* Wp      = (const float*)d_in[2];
    const float* bp      = (const float*)d_in[3];
    const float* qkv_w   = (const float*)d_in[4];
    const float* qkv_b   = (const float*)d_in[5];
    const float* ln_w    = (const float*)d_in[6];
    const float* ln_b    = (const float*)d_in[7];
    const float* mlp1_w  = (const float*)d_in[8];
    const float* mlp1_b  = (const float*)d_in[9];
    const float* mlp2_w  = (const float*)d_in[10];
    const float* mlp2_b  = (const float*)d_in[11];
    const float* head1_w = (const float*)d_in[12];
    const float* head1_b = (const float*)d_in[13];
    const float* head2_w = (const float*)d_in[14];
    const float* head2_b = (const float*)d_in[15];
    float* outp = (float*)d_out;

    char* ws = (char*)d_ws;
    size_t off = 0;
    auto alloc = [&](size_t bytes) -> void* {
        void* p = ws + off; off += (bytes + 255) & ~(size_t)255; return p;
    };
    float* s_out = (float*)alloc((size_t)M_ROWS * D_ * 4);
    float* s_r   = (float*)alloc((size_t)M_ROWS * D_ * 4);
    f16*   s_h   = (f16*)  alloc((size_t)M_ROWS * D_ * 2);
    void*  s_big = alloc((size_t)M_ROWS * MLP_H_ * 2);
    f16*   w_qkv_t  = (f16*)alloc((size_t)2 * 768 * 256 * 2);
    f16*   w_mlp1_t = (f16*)alloc((size_t)2 * 2048 * 256 * 2);
    f16*   w_mlp2_t = (f16*)alloc((size_t)2 * 256 * 2048 * 2);
    f16*   wpT      = (f16*)alloc((size_t)256 * 64 * 2);
    f16*   s_flat   = s_h;       // alias: dead after mlp1 of layer 2
    f16*   s_qkv = (f16*)s_big;
    f16*   s_m   = (f16*)s_big;
    float* s_part = (float*)s_big;

    dim3 blk(256);

    for (int i = 0; i < 2; ++i) {
        transpose_cvt<<<dim3(768 / 32, 256 / 32), blk, 0, stream>>>(
            qkv_w + (size_t)i * D_ * 768, w_qkv_t + (size_t)i * 768 * 256, 256, 768);
        transpose_cvt<<<dim3(2048 / 32, 256 / 32), blk, 0, stream>>>(
            mlp1_w + (size_t)i * D_ * 2048, w_mlp1_t + (size_t)i * 2048 * 256, 256, 2048);
        transpose_cvt<<<dim3(256 / 32, 2048 / 32), blk, 0, stream>>>(
            mlp2_w + (size_t)i * 2048 * 256, w_mlp2_t + (size_t)i * 256 * 2048, 2048, 256);
    }
    wpt_build<<<dim3(64), blk, 0, stream>>>(Wp, wpT);
    patch_mfma<<<dim3(B_), blk, 0, stream>>>(x, cls, wpT, bp, s_out);

    for (int i = 0; i < 2; ++i) {
        const float* lw = ln_w + (size_t)i * T1_ * D_;
        const float* lb = ln_b + (size_t)i * T1_ * D_;
        ln_kernel<<<dim3(B_), dim3(1024), 0, stream>>>(s_out, lw, lb, s_h);
        gemm_f16<0, f16><<<dim3(768 / 128, M_ROWS / 128), blk, 0, stream>>>(
            s_h, w_qkv_t + (size_t)i * 768 * 256, qkv_b + (size_t)i * 768,
            nullptr, s_qkv, nullptr, M_ROWS, 768, 256);
        attn_kernel<<<dim3(B_ * H_), blk, 0, stream>>>(s_qkv, s_out, s_r);
        ln_kernel<<<dim3(B_), dim3(1024), 0, stream>>>(s_r, lw, lb, s_h);
        gemm_f16<1, f16><<<dim3(MLP_H_ / 128, M_ROWS / 128), blk, 0, stream>>>(
            s_h, w_mlp1_t + (size_t)i * 2048 * 256, mlp1_b + (size_t)i * MLP_H_,
            nullptr, s_m, nullptr, M_ROWS, MLP_H_, 256);
        if (i == 0) {
            gemm_f16<2, float><<<dim3(D_ / 128, M_ROWS / 128), blk, 0, stream>>>(
                s_m, w_mlp2_t + (size_t)i * 256 * 2048, mlp2_b + (size_t)i * D_,
                s_r, s_out, nullptr, M_ROWS, D_, MLP_H_);
        } else {
            gemm_f16<3, float><<<dim3(D_ / 128, M_ROWS / 128), blk, 0, stream>>>(
                s_m, w_mlp2_t + (size_t)i * 256 * 2048, mlp2_b + (size_t)i * D_,
                s_r, s_out, s_flat, M_ROWS, D_, MLP_H_);
        }
    }

    gemm_head1<<<dim3(HEAD_H_ / 64, 4), blk, 0, stream>>>(s_flat, head1_w, s_part);
    head2_fused<<<dim3(B_), blk, 0, stream>>>(s_part, head1_b, head2_w, head2_b, outp);
}